// Round 4
// baseline (569.567 us; speedup 1.0000x reference)
//
#include <hip/hip_runtime.h>
#include <hip/hip_bf16.h>

// Bahdanau attention, restructured:
//   tanh_in[b,t,k] = e[b,t,:]@(U@Wa) + cvec[b,k]   (one 131072x512x512 bf16 GEMM)
//   cij[b,t] = sum_k tanh(tanh_in)*V[k]            (fused epilogue, no [B,T,H] tensor)
//   alphas = softmax(cij); out = sum_t alphas*e
// Shapes: B=32 T=4096 D=512 H=512.
//
// R4: (a) gemm A-prefetch issued AFTER barrier #2 so it flies during the MFMA
// phase and is drained at the next iter's barrier #1 (hides ~2/3 of HBM lat);
// (b) cij epilogue via LDS cross-wave reduce + direct store (no atomics, no
// memset); (c) dens1+cvec+uwa fused into k_prep (no atomics, 3 fewer launches,
// hipMemsetAsync removed); (d) wsum 4-stream ILP.
// Known fixed overhead per replay (harness, uncontrollable): ~160us 1GiB d_ws
// 0xAA poison (fillBufferAligned, top-5 in R3) + input restore.

#define BB 32
#define TT 4096
#define DD 512
#define HH 512
#define BK 64

typedef short s16x8 __attribute__((ext_vector_type(8)));
typedef float f32x4 __attribute__((ext_vector_type(4)));

union FU { float f; unsigned u; };

static __device__ __forceinline__ unsigned pack_bf16_trunc(float a, float b) {
    FU ua, ub; ua.f = a; ub.f = b;
    return (ua.u >> 16) | (ub.u & 0xffff0000u);
}

static __device__ __forceinline__ unsigned short f2bf_rne(float x) {
    FU v; v.f = x;
    unsigned u = v.u;
    u = u + 0x7fffu + ((u >> 16) & 1u);
    return (unsigned short)(u >> 16);
}

static __device__ __forceinline__ float tanh_fast(float x) {
    float e = __expf(2.0f * x);
    return 1.0f - 2.0f * __builtin_amdgcn_rcpf(e + 1.0f);
}

// async global->LDS, 16B/lane. LDS dest = wave-uniform base + lane*16.
static __device__ __forceinline__ void gload_lds16(const void* g, void* l) {
    __builtin_amdgcn_global_load_lds(
        (const __attribute__((address_space(1))) unsigned int*)g,
        (__attribute__((address_space(3))) unsigned int*)l, 16, 0, 0);
}

// ---------------------------------------------------------------------------
// k_prep, 96 blocks:
//  blocks 0..31  : b = blockIdx; g[b,:]=hs@W+bias (LDS), cvec[b,:]=g@Wa+ba. No atomics.
//  blocks 32..95 : UWaT[n][d] = bf16(sum_h U[d,h]*Wa[h,n]), 8 d-rows per block.
__global__ void k_prep(const float* __restrict__ hs, const float* __restrict__ W,
                       const float* __restrict__ bias, const float* __restrict__ Wa,
                       const float* __restrict__ ba, const float* __restrict__ U,
                       float* __restrict__ cvec, unsigned short* __restrict__ UWaT) {
    int bi = blockIdx.x;
    int tid = threadIdx.x;
    __shared__ float sm[8 * DD];   // union: {hsb[512], gs[512]} | Us[8][512]
    if (bi < 32) {
        int b = bi;
        float* hsb = sm;
        float* gs = sm + DD;
        hsb[tid] = hs[b * DD + tid];
        hsb[tid + 256] = hs[b * DD + tid + 256];
        __syncthreads();
        float a0 = bias[tid], a1 = bias[tid + 256];
        #pragma unroll 4
        for (int d = 0; d < DD; ++d) {
            float h = hsb[d];
            a0 = fmaf(h, W[(size_t)d * HH + tid], a0);
            a1 = fmaf(h, W[(size_t)d * HH + tid + 256], a1);
        }
        gs[tid] = a0;
        gs[tid + 256] = a1;
        __syncthreads();
        float c0 = ba[tid], c1 = ba[tid + 256];
        #pragma unroll 4
        for (int h = 0; h < HH; ++h) {
            float g = gs[h];
            c0 = fmaf(g, Wa[(size_t)h * HH + tid], c0);
            c1 = fmaf(g, Wa[(size_t)h * HH + tid + 256], c1);
        }
        cvec[b * HH + tid] = c0;
        cvec[b * HH + tid + 256] = c1;
    } else {
        int d0 = (bi - 32) * 8;
        float (*Us)[DD] = (float (*)[DD])sm;
        #pragma unroll
        for (int i = 0; i < 16; ++i) {
            int idx = i * 256 + tid;
            Us[idx >> 9][idx & 511] = U[(size_t)(d0 + (idx >> 9)) * HH + (idx & 511)];
        }
        __syncthreads();
        float acc[8][2] = {};
        #pragma unroll 2
        for (int h = 0; h < DD; ++h) {
            float w0 = Wa[(size_t)h * HH + tid];
            float w1 = Wa[(size_t)h * HH + 256 + tid];
            #pragma unroll
            for (int dd = 0; dd < 8; ++dd) {
                float u = Us[dd][h];
                acc[dd][0] = fmaf(u, w0, acc[dd][0]);
                acc[dd][1] = fmaf(u, w1, acc[dd][1]);
            }
        }
        #pragma unroll
        for (int dd = 0; dd < 8; ++dd) {
            UWaT[(size_t)tid * DD + d0 + dd] = f2bf_rne(acc[dd][0]);
            UWaT[(size_t)(tid + 256) * DD + d0 + dd] = f2bf_rne(acc[dd][1]);
        }
    }
}

// ---------------------------------------------------------------------------
// GEMM tile 64(M) x 512(N full), BK=64, 2048 blocks x 256 thr (4 waves, wave w
// -> cols [w*128,+128)). e fetched exactly once. B staged per k0 via coalesced
// global_load_lds (8 rows x 8 16B-chunks per instr, XOR chunk swizzle).
// A software-pipelined: global float4 loads for iter k+1 issued AFTER barrier
// #2 of iter k, in flight through the MFMA phase, drained at barrier #1 of k+1.
// LDS 16B-unit layouts:
//   Bs unit = col*8 + (g ^ (col&7))   As unit = g*64 + (row ^ g)   (both conflict-free)
__global__ void __launch_bounds__(256, 2) k_gemm_tanh(
    const float* __restrict__ e, const unsigned short* __restrict__ Bt,
    const float* __restrict__ cvec, const float* __restrict__ V,
    float* __restrict__ cij) {
    int tid = threadIdx.x;
    int m0 = blockIdx.x * 64;
    int lane = tid & 63, w = tid >> 6;
    int wn = w * 128;
    int lcol = lane & 15, q = lane >> 4;
    int rl = lane >> 3, gg = lane & 7;

    __shared__ __align__(16) unsigned short As[64 * BK];    // 8 KB
    __shared__ __align__(16) unsigned short Bs[512 * BK];   // 64 KB

    f32x4 acc[4][8] = {};

    // this thread's A staging coords (row, 16B-chunk) for its 4 loads
    int arow[4], ac4[4];
    #pragma unroll
    for (int it = 0; it < 4; ++it) {
        int idx = it * 256 + tid;
        arow[it] = idx >> 4;
        ac4[it] = idx & 15;
    }
    const float* Abase = e + (size_t)m0 * DD;

    // prefetch iter 0
    float4 av[4];
    #pragma unroll
    for (int it = 0; it < 4; ++it)
        av[it] = *(const float4*)(Abase + (size_t)arow[it] * DD + ac4[it] * 4);

    for (int k0 = 0; k0 < DD; k0 += BK) {
        if (k0) __syncthreads();   // barrier #1: prev compute done; drains av
        // B: 16 coalesced global_load_lds per wave (wave w stages rows [w*128,+128))
        #pragma unroll
        for (int u = 0; u < 16; ++u) {
            int n0 = w * 128 + u * 8;
            const unsigned short* gp =
                Bt + (size_t)(n0 + rl) * DD + k0 + ((gg ^ rl) << 3);
            gload_lds16(gp, &Bs[n0 * 64]);
        }
        // convert prefetched A -> As (swizzled ds_write_b64)
        #pragma unroll
        for (int it = 0; it < 4; ++it) {
            uint2 wv;
            wv.x = pack_bf16_trunc(av[it].x, av[it].y);
            wv.y = pack_bf16_trunc(av[it].z, av[it].w);
            int g = ac4[it] >> 1, half = ac4[it] & 1;
            *(uint2*)&As[(g * 64 + (arow[it] ^ g)) * 8 + half * 4] = wv;
        }
        __syncthreads();           // barrier #2: drains B load_lds
        // issue next iter's A loads now -> in flight during MFMA phase
        if (k0 < DD - BK) {
            #pragma unroll
            for (int it = 0; it < 4; ++it)
                av[it] = *(const float4*)(Abase + (size_t)arow[it] * DD +
                                          (k0 + BK) + ac4[it] * 4);
        }
        #pragma unroll
        for (int ks = 0; ks < BK; ks += 32) {
            int gk = ks >> 3;  // 0 or 4
            s16x8 af[4], bfr[8];
            #pragma unroll
            for (int i = 0; i < 4; ++i) {
                int row = i * 16 + lcol, g = gk + q;
                af[i] = *(const s16x8*)&As[(g * 64 + (row ^ g)) * 8];
            }
            #pragma unroll
            for (int j = 0; j < 8; ++j) {
                int col = wn + j * 16 + lcol, g = gk + q;
                bfr[j] = *(const s16x8*)&Bs[col * 64 + ((g ^ (col & 7)) << 3)];
            }
            #pragma unroll
            for (int i = 0; i < 4; ++i)
                #pragma unroll
                for (int j = 0; j < 8; ++j)
                    acc[i][j] = __builtin_amdgcn_mfma_f32_16x16x32_bf16(
                        af[i], bfr[j], acc[i][j], 0, 0, 0);
        }
    }

    // Epilogue: cij[row] = sum over all 512 cols of tanh(acc+cvec)*V.
    // C/D layout: col = lane&15, row = (lane>>4)*4 + reg.
    // Per-wave shfl reduce over 16 col-lanes, then cross-wave LDS reduce.
    __syncthreads();               // done with As; reuse as reduction buffer
    float* red = (float*)As;       // 4 waves x 64 rows
    int b = m0 >> 12;
    float cvv[8], Vv[8];
    #pragma unroll
    for (int j = 0; j < 8; ++j) {
        int h = wn + j * 16 + lcol;
        cvv[j] = cvec[b * HH + h];
        Vv[j] = V[h];
    }
    #pragma unroll
    for (int i = 0; i < 4; ++i) {
        #pragma unroll
        for (int r = 0; r < 4; ++r) {
            float s = 0.0f;
            #pragma unroll
            for (int j = 0; j < 8; ++j)
                s = fmaf(tanh_fast(acc[i][j][r] + cvv[j]), Vv[j], s);
            s += __shfl_xor(s, 1);
            s += __shfl_xor(s, 2);
            s += __shfl_xor(s, 4);
            s += __shfl_xor(s, 8);
            if (lcol == 0)
                red[w * 64 + i * 16 + q * 4 + r] = s;
        }
    }
    __syncthreads();
    if (tid < 64)
        cij[m0 + tid] = red[tid] + red[64 + tid] + red[128 + tid] + red[192 + tid];
}

// ---------------------------------------------------------------------------
// softmax over T per batch.
__global__ void k_softmax(const float* __restrict__ cij, float* __restrict__ alphas) {
    int b = blockIdx.x, tid = threadIdx.x;
    const float* row = cij + (size_t)b * TT;
    __shared__ float red[4];
    float m = -1e30f;
    for (int t = tid; t < TT; t += 256) m = fmaxf(m, row[t]);
    #pragma unroll
    for (int o = 1; o < 64; o <<= 1) m = fmaxf(m, __shfl_xor(m, o));
    if ((tid & 63) == 0) red[tid >> 6] = m;
    __syncthreads();
    m = fmaxf(fmaxf(red[0], red[1]), fmaxf(red[2], red[3]));
    __syncthreads();
    float sum = 0.0f;
    for (int t = tid; t < TT; t += 256) sum += __expf(row[t] - m);
    #pragma unroll
    for (int o = 1; o < 64; o <<= 1) sum += __shfl_xor(sum, o);
    if ((tid & 63) == 0) red[tid >> 6] = sum;
    __syncthreads();
    float inv = 1.0f / (red[0] + red[1] + red[2] + red[3]);
    for (int t = tid; t < TT; t += 256)
        alphas[(size_t)b * TT + t] = __expf(row[t] - m) * inv;
}

// partial weighted sums, no atomics; 4 independent load streams.
// block = (b, 64-t chunk) -> pw[b][chunk][0:512]. 2048 blocks, 268MB stream.
__global__ void k_wsum(const float* __restrict__ e, const float* __restrict__ alphas,
                       float* __restrict__ pw) {
    int b = blockIdx.x >> 6;
    int chunk = blockIdx.x & 63;
    int tid = threadIdx.x;
    int half = tid >> 7, f4 = tid & 127;
    const float* base = e + (size_t)b * TT * DD + (size_t)chunk * 64 * DD + f4 * 4;
    const float* al = alphas + (size_t)b * TT + chunk * 64;
    f32x4 a0 = {0,0,0,0}, a1 = {0,0,0,0}, a2 = {0,0,0,0}, a3 = {0,0,0,0};
    for (int it = 0; it < 8; ++it) {
        int t = it * 8 + half;
        float w0 = al[t], w1 = al[t + 2], w2 = al[t + 4], w3 = al[t + 6];
        a0 += w0 * *(const f32x4*)(base + (size_t)t * DD);
        a1 += w1 * *(const f32x4*)(base + (size_t)(t + 2) * DD);
        a2 += w2 * *(const f32x4*)(base + (size_t)(t + 4) * DD);
        a3 += w3 * *(const f32x4*)(base + (size_t)(t + 6) * DD);
    }
    a0 += a1; a2 += a3; a0 += a2;
    __shared__ f32x4 red[128];
    if (half == 1) red[f4] = a0;
    __syncthreads();
    if (half == 0) {
        a0 += red[f4];
        *(f32x4*)&pw[((size_t)(b * 64 + chunk)) * DD + f4 * 4] = a0;
    }
}

// out[b,d] = sum_chunk pw[b][chunk][d]. 4MB read.
__global__ void k_wred(const float* __restrict__ pw, float* __restrict__ out) {
    int b = blockIdx.x, tid = threadIdx.x;
    float2 acc = {0.0f, 0.0f};
    const float* base = pw + (size_t)b * 64 * DD;
    #pragma unroll 4
    for (int c = 0; c < 64; ++c) {
        float2 v = *(const float2*)(base + (size_t)c * DD + tid * 2);
        acc.x += v.x;
        acc.y += v.y;
    }
    *(float2*)&out[b * DD + tid * 2] = acc;
}

// ---------------------------------------------------------------------------
extern "C" void kernel_launch(void* const* d_in, const int* in_sizes, int n_in,
                              void* d_out, int out_size, void* d_ws, size_t ws_size,
                              hipStream_t stream) {
    const float* hs   = (const float*)d_in[0];   // [32,512]
    const float* e    = (const float*)d_in[1];   // [32,4096,512]
    const float* W    = (const float*)d_in[2];   // [512,512]
    const float* U    = (const float*)d_in[3];   // [512,512]
    const float* V    = (const float*)d_in[4];   // [512]
    const float* bias = (const float*)d_in[5];   // [512]
    const float* Wa   = (const float*)d_in[6];   // [512,512]
    const float* ba   = (const float*)d_in[7];   // [512]

    float* out    = (float*)d_out;               // [32,512] then alphas [32,4096]
    float* alphas = out + BB * DD;

    float*          cij  = (float*)d_ws;                              // 512 KB
    float*          cvec = (float*)((char*)d_ws + 524288);            // 64 KB
    unsigned short* Bt   = (unsigned short*)((char*)d_ws + 589824);   // 512 KB bf16
    float*          pw   = (float*)((char*)d_ws + 1179648);           // 4 MB

    // no memsets needed: every workspace word consumed is written first
    // (cvec/Bt by k_prep, cij stored directly by k_gemm_tanh, pw by k_wsum).

    k_prep<<<96, 256, 0, stream>>>(hs, W, bias, Wa, ba, U, cvec, Bt);
    k_gemm_tanh<<<2048, 256, 0, stream>>>(e, Bt, cvec, V, cij);
    k_softmax<<<BB, 256, 0, stream>>>(cij, alphas);
    k_wsum<<<BB * 64, 256, 0, stream>>>(e, alphas, pw);
    k_wred<<<BB, 256, 0, stream>>>(pw, out);
}